// Round 8
// baseline (7265.392 us; speedup 1.0000x reference)
//
#include <hip/hip_runtime.h>
#include <hip/hip_bf16.h>
#include <math.h>

#define TT 1024
#define BB 64
#define IND 128
#define HID 512
#define OUTD 128

// Workspace layout (float offsets):
//  wih4 : [32][512][4]  packed W_ih^T (float4 along k)   @ 0          (65536 f)
//  wfc4 : [128][128][4] packed W_fc^T (float4 along h)   @ 65536      (65536 f)
//  xp   : [T][B][HID] f32                                @ 131072     (33554432 f)
//  r    : [T][B][HID] bf16                               @ 33685504 f
//  hbuf : [2][B][HID] f32 (double-buffered h exchange)   @ 50462720   (65536 f)
//  cnt  : [B][32] u32 (per-batch step counters, padded)  @ 50528256   (2048 f)

#define WIH4_OFF 0
#define WFC4_OFF 65536
#define XP_OFF   131072
#define R_OFF    33685504
#define HBUF_OFF 50462720
#define CNT_OFF  50528256

__device__ __forceinline__ float bf2f(unsigned short u) {
    union { unsigned int i; float f; } v; v.i = ((unsigned int)u) << 16; return v.f;
}
__device__ __forceinline__ unsigned short f2bf(float f) {
    union { unsigned int i; float f; } v; v.f = f;
    unsigned int i = v.i;
    unsigned int r = (i + 0x7FFFu + ((i >> 16) & 1u)) >> 16;
    return (unsigned short)r;
}

// ---- prep: transpose + pack W_ih, W_fc ----------------------------------
__global__ void k_prep(const float* __restrict__ wih, const float* __restrict__ wfc,
                       float* __restrict__ ws) {
    int fid = blockIdx.x * 256 + threadIdx.x;
    if (fid < 16384) {                        // W_ih: [512][128] -> [32][512] float4
        int k4 = fid >> 9, j = fid & 511;
        ((float4*)(ws + WIH4_OFF))[fid] = ((const float4*)wih)[j * 32 + k4];
    } else if (fid < 32768) {                 // W_fc: [128][512] -> [128][128] float4
        int f = fid - 16384;
        int h4 = f >> 7, o = f & 127;
        ((float4*)(ws + WFC4_OFF))[f] = ((const float4*)wfc)[o * 128 + h4];
    }
}

// ---- phase 1: xp[t][b][j] = x[t,b,:] . W_ih[j,:] + b_ih[j] + b_hh[j] ----
__global__ __launch_bounds__(512) void k_xp(const float* __restrict__ x,
                                            const float* __restrict__ wih4,
                                            const float* __restrict__ bih,
                                            const float* __restrict__ bhh,
                                            float* __restrict__ xp) {
    int t = blockIdx.x, bg = blockIdx.y;      // bg: group of 16 batches
    int j = threadIdx.x;                      // 0..511
    __shared__ float4 xs[16 * 32];            // [16 b][32 k4]
    const float4* xsrc = (const float4*)(x + ((size_t)t * BB + bg * 16) * IND);
    xs[j] = xsrc[j];
    __syncthreads();

    float bias = bih[j] + bhh[j];
    float acc[16];
#pragma unroll
    for (int b = 0; b < 16; b++) acc[b] = bias;

    const float4* wp = (const float4*)wih4;   // [32][512]
#pragma unroll 4
    for (int k4 = 0; k4 < 32; k4++) {
        float4 w = wp[k4 * 512 + j];
#pragma unroll
        for (int b = 0; b < 16; b++) {
            float4 xv = xs[b * 32 + k4];
            acc[b] += w.x * xv.x + w.y * xv.y + w.z * xv.z + w.w * xv.w;
        }
    }
    float* dst = xp + ((size_t)t * BB + bg * 16) * HID + j;
#pragma unroll
    for (int b = 0; b < 16; b++) dst[(size_t)b * HID] = acc[b];
}

// ---- phase 2: persistent-weight recurrence ------------------------------
// Grid: 256 blocks = 64 batches x 4 row-groups. tid = j*4+q: thread owns
// row (g*128+j), k-window q*128..+127 (128 weights, asm-pinned in VGPRs;
// full-row dot via 2 shfl_xor over the q lanes). Sync per step uses the
// ROUND-3-PROVEN protocol: relaxed agent h-stores -> __syncthreads (drains
// vmcnt) -> tid0 fetch_add RELEASE + ACQUIRE poll on a per-batch MONOTONIC
// counter (cumulative target => immune to overshoot/skip cascades that
// killed the tagged-packet design in rounds 6/7) -> __syncthreads ->
// relaxed agent h-loads into LDS.
__global__ __launch_bounds__(512, 2) void k_rnn(const float* __restrict__ xp,
                                                const float* __restrict__ whh,
                                                unsigned short* __restrict__ r,
                                                float* __restrict__ out,
                                                float* __restrict__ hbuf,
                                                unsigned int* __restrict__ cnt) {
    const int b = blockIdx.x & 63;
    const int g = blockIdx.x >> 6;
    const int tid = threadIdx.x;
    const int j = tid >> 2;                   // 0..127
    const int q = tid & 3;                    // 0..3 (lane bits 0-1)
    const int row = g * 128 + j;              // output row in [0,512)

    // ---- load + pin W_hh[row][q*128 .. q*128+127] into 128 VGPRs ----
    float w[128];
    {
        const float4* wsrc = (const float4*)(whh + (size_t)row * HID + q * 128);
#pragma unroll
        for (int i = 0; i < 32; i++) {
            float4 v = wsrc[i];
            w[4 * i] = v.x; w[4 * i + 1] = v.y; w[4 * i + 2] = v.z; w[4 * i + 3] = v.w;
        }
    }
#pragma unroll
    for (int i = 0; i < 128; i++) asm volatile("" : "+v"(w[i]));  // forbid remat/sink

    // h in LDS, padded +4 floats per 128-chunk so the 4 q-lanes' float4
    // reads hit disjoint bank groups (banks (i+q)*4.. vs 4-way conflict).
    __shared__ float hs[528];
    hs[tid + 4 * (tid >> 7)] =
        __hip_atomic_load(hbuf + (size_t)b * HID + tid,
                          __ATOMIC_RELAXED, __HIP_MEMORY_SCOPE_AGENT);
    __syncthreads();

    const float* xpb = xp + (size_t)b * HID + row;
    unsigned short* rb = r + (size_t)b * HID + row;
    unsigned int* cb = cnt + b * 32;

    float xpv = xpb[0];
    float hn = 0.f;

    for (int t = 0; t < TT; t++) {
        // --- full-row partial dot from pinned registers ---
        const float4* h4 = (const float4*)(hs + q * 132);
        float a0 = 0.f, a1 = 0.f, a2 = 0.f, a3 = 0.f;
#pragma unroll
        for (int i = 0; i < 32; i++) {
            float4 hv = h4[i];
            a0 += w[4 * i + 0] * hv.x;
            a1 += w[4 * i + 1] * hv.y;
            a2 += w[4 * i + 2] * hv.z;
            a3 += w[4 * i + 3] * hv.w;
        }
        float s = (a0 + a1) + (a2 + a3);
        s += __shfl_xor(s, 1, 64);            // reduce across q lanes (bits 0-1)
        s += __shfl_xor(s, 2, 64);
        hn = tanhf(s + xpv);

        const int par1 = (t + 1) & 1;
        if (q == 0) {
            __hip_atomic_store(hbuf + (size_t)par1 * (BB * HID) + (size_t)b * HID + row,
                               hn, __ATOMIC_RELAXED, __HIP_MEMORY_SCOPE_AGENT);
            rb[(size_t)t * BB * HID] = f2bf(hn);
        }
        float xpn = (t + 1 < TT) ? xpb[(size_t)(t + 1) * BB * HID] : 0.f;  // prefetch
        __syncthreads();                      // drains vmcnt: h slice globally visible

        if (tid == 0) {
            __hip_atomic_fetch_add(cb, 1u, __ATOMIC_RELEASE, __HIP_MEMORY_SCOPE_AGENT);
            unsigned int target = 4u * (unsigned)(t + 1);
            long polls = 0;
            long lim = (t == 0) ? (1L << 22) : (1L << 17);  // watchdog: fail loud
            while (__hip_atomic_load(cb, __ATOMIC_ACQUIRE, __HIP_MEMORY_SCOPE_AGENT) < target) {
                if (++polls > lim) break;
            }
        }
        __syncthreads();

        hs[tid + 4 * (tid >> 7)] =
            __hip_atomic_load(hbuf + (size_t)par1 * (BB * HID) + (size_t)b * HID + tid,
                              __ATOMIC_RELAXED, __HIP_MEMORY_SCOPE_AGENT);
        xpv = xpn;
        __syncthreads();
    }

    if (q == 0)
        out[(size_t)TT * BB * OUTD + (size_t)b * HID + row] = hn;  // h_last
}

// ---- phase 3: y[t][b][o] = r[t,b,:] . W_fc[o,:] + b_fc[o] ---------------
__global__ __launch_bounds__(512) void k_y(const unsigned short* __restrict__ r,
                                           const float* __restrict__ wfc4,
                                           const float* __restrict__ bfc,
                                           float* __restrict__ y) {
    int t = blockIdx.x, bg = blockIdx.y;
    int tid = threadIdx.x;
    int o = tid & 127, bq = tid >> 7;
    __shared__ float rs[16 * 512];
    const unsigned short* rsrc = r + ((size_t)t * BB + bg * 16) * HID;
    for (int i = tid; i < 16 * 512 / 2; i += 512) {
        ushort2 u = ((const ushort2*)rsrc)[i];
        rs[2 * i] = bf2f(u.x);
        rs[2 * i + 1] = bf2f(u.y);
    }
    __syncthreads();

    float acc[4] = {0.f, 0.f, 0.f, 0.f};
    const float4* wp = (const float4*)wfc4;
    const float4* rs4 = (const float4*)rs;
#pragma unroll 4
    for (int h4 = 0; h4 < 128; h4++) {
        float4 w = wp[h4 * 128 + o];
#pragma unroll
        for (int bb = 0; bb < 4; bb++) {
            float4 rv = rs4[(bq * 4 + bb) * 128 + h4];
            acc[bb] += w.x * rv.x + w.y * rv.y + w.z * rv.z + w.w * rv.w;
        }
    }
    float bias = bfc[o];
    float* dst = y + ((size_t)t * BB + bg * 16 + bq * 4) * OUTD + o;
#pragma unroll
    for (int bb = 0; bb < 4; bb++) dst[(size_t)bb * OUTD] = acc[bb] + bias;
}

extern "C" void kernel_launch(void* const* d_in, const int* in_sizes, int n_in,
                              void* d_out, int out_size, void* d_ws, size_t ws_size,
                              hipStream_t stream) {
    (void)in_sizes; (void)n_in; (void)out_size; (void)ws_size;
    const float* x    = (const float*)d_in[0];
    const float* h0   = (const float*)d_in[1];
    const float* wih  = (const float*)d_in[2];
    const float* whh  = (const float*)d_in[3];
    const float* bih  = (const float*)d_in[4];
    const float* bhh  = (const float*)d_in[5];
    const float* wfc  = (const float*)d_in[6];
    const float* bfc  = (const float*)d_in[7];
    float* out = (float*)d_out;

    float* ws = (float*)d_ws;
    float* wih4 = ws + WIH4_OFF;
    float* wfc4 = ws + WFC4_OFF;
    float* xp   = ws + XP_OFF;
    unsigned short* rbuf = (unsigned short*)(ws + R_OFF);
    float* hbuf = ws + HBUF_OFF;
    unsigned int* cnt = (unsigned int*)(ws + CNT_OFF);

    hipMemsetAsync(cnt, 0, 64 * 32 * sizeof(unsigned int), stream);
    hipMemcpyAsync(hbuf, h0, (size_t)BB * HID * sizeof(float),
                   hipMemcpyDeviceToDevice, stream);
    hipLaunchKernelGGL(k_prep, dim3(128), dim3(256), 0, stream, wih, wfc, ws);
    hipLaunchKernelGGL(k_xp, dim3(TT, BB / 16), dim3(512), 0, stream, x, wih4, bih, bhh, xp);
    hipLaunchKernelGGL(k_rnn, dim3(256), dim3(512), 0, stream, xp, whh, rbuf, out, hbuf, cnt);
    hipLaunchKernelGGL(k_y, dim3(TT, BB / 16), dim3(512), 0, stream, rbuf, wfc4, bfc, out);
}